// Round 5
// baseline (422.653 us; speedup 1.0000x reference)
//
#include <hip/hip_runtime.h>
#include <math.h>

#define D_DIM 128
#define N_DST 50000
#define N_SRC 50000
#define NE    800000
#define NEG_SLOPE 0.2f

#define NB        196      // coarse buckets: dst>>8
#define CAP       4608     // fixed bucket capacity (λ=4082, +8.2σ)
#define CHUNK     8192
#define NBLK_REL  98       // ceil(NE / CHUNK)
#define GEMM_BLKS 196      // ceil(N_SRC / 256) — 256 rows/block (8 waves × 32 rows)
#define GEMM_GRID (3 * GEMM_BLKS)   // 588
#define ER_PB     86       // er rows per gemm block: 588 * 86 = 50568 >= 50000
#define SEM_GRID  512      // persistent semantic blocks
#define SEM_TILES ((3 * N_DST + 63) / 64)

typedef unsigned short ushort_t;
using f32x4  = __attribute__((ext_vector_type(4))) float;
using bf16x8 = __attribute__((ext_vector_type(8))) short;

__device__ __forceinline__ ushort_t f2bf(float x) {
    unsigned u = __float_as_uint(x);
    unsigned r = (u + 0x7fffu + ((u >> 16) & 1u)) >> 16;
    return (ushort_t)r;
}
__device__ __forceinline__ float bf2f(ushort_t b) {
    return __uint_as_float(((unsigned)b) << 16);
}
__device__ __forceinline__ float bflo(unsigned u) { return __uint_as_float(u << 16); }
__device__ __forceinline__ float bfhi(unsigned u) { return __uint_as_float(u & 0xffff0000u); }
__device__ __forceinline__ float tanh_fast(float x) {
    float e = __expf(2.f * x);
    return 1.f - 2.f / (e + 1.f);
}

// convert 8 fp32 -> split bf16 (hi round-nearest-even, lo truncated)
__device__ __forceinline__ void cvt8(float4 f0, float4 f1, bf16x8& hi, bf16x8& lo) {
    float f[8] = {f0.x, f0.y, f0.z, f0.w, f1.x, f1.y, f1.z, f1.w};
    #pragma unroll
    for (int i = 0; i < 8; i++) {
        ushort_t h = f2bf(f[i]);
        hi[i] = (short)h;
        lo[i] = (short)(ushort_t)(__float_as_uint(f[i] - bf2f(h)) >> 16);
    }
}

// ---------------------------------------------------------------------------
// merged prep: [0,3) wv_r = Wg_r @ ar_r ; [3,67) W1^T -> bf16 Wt_g ;
// [67,259) Wg^T -> fragment-linear split-bf16 B operand table Bv.
__global__ __launch_bounds__(256) void vecprep_kernel(
        const float* __restrict__ Wg0, const float* __restrict__ Wg1,
        const float* __restrict__ Wg2,
        const float* __restrict__ ar0, const float* __restrict__ ar1,
        const float* __restrict__ ar2,
        const float* __restrict__ W1,
        float* __restrict__ wv, ushort_t* __restrict__ Wt_g,
        ushort_t* __restrict__ Bv) {
    int bx = blockIdx.x, tid = threadIdx.x;
    if (bx < 3) {
        if (tid < 128) {
            const float* W  = bx == 0 ? Wg0 : (bx == 1 ? Wg1 : Wg2);
            const float* ar = bx == 0 ? ar0 : (bx == 1 ? ar1 : ar2);
            float sar = 0.f;
            for (int j = 0; j < D_DIM; j++) sar = fmaf(W[tid * D_DIM + j], ar[j], sar);
            wv[bx * D_DIM + tid] = sar;
        }
    } else if (bx < 67) {
        int idx = (bx - 3) * 256 + tid;           // 16384
        int k = idx >> 7, n = idx & 127;
        Wt_g[n * 128 + k] = f2bf(W1[idx]);
    } else {
        int q = bx - 67;
        int rel = q >> 6;
        int idx = (q & 63) * 256 + tid;           // 16384 per rel
        const float* W = rel == 0 ? Wg0 : (rel == 1 ? Wg1 : Wg2);
        int k = idx >> 7, n = idx & 127;          // value = Wg[k][n] = B^T[n][k]
        float v = W[idx];
        ushort_t hi = f2bf(v);
        ushort_t lo = f2bf(v - bf2f(hi));
        int nt = n >> 4, l15 = n & 15;
        int kc = k >> 5, quad = (k >> 3) & 3, e = k & 7;
        int h2 = nt >> 2, n4 = nt & 3;
        int lane = quad * 16 + l15;
        int fh = kc * 16 + h2 * 8 + n4;           // hl=0
        ushort_t* dst = Bv + (size_t)rel * 32768;
        dst[(fh)     * 512 + lane * 8 + e] = hi;
        dst[(fh + 4) * 512 + lane * 8 + e] = lo;  // hl=1 → +4 frags
    }
}

// ---------------------------------------------------------------------------
// bucket scatter, fixed-capacity regions (no hist/scan passes).
__global__ __launch_bounds__(256) void bucket_scatter_kernel(
        const int* __restrict__ d0, const int* __restrict__ d1, const int* __restrict__ d2,
        const int* __restrict__ s0, const int* __restrict__ s1, const int* __restrict__ s2,
        int* __restrict__ bucketCur, int2* __restrict__ pairs) {
    __shared__ int cnt[NB], base[NB], cur[NB];
    int bx = blockIdx.x;
    int r = bx / NBLK_REL, blk = bx % NBLK_REL;
    const int* dd = r == 0 ? d0 : (r == 1 ? d1 : d2);
    const int* ss = r == 0 ? s0 : (r == 1 ? s1 : s2);
    int tid = threadIdx.x;
    if (tid < NB) { cnt[tid] = 0; cur[tid] = 0; }
    __syncthreads();
    int e0 = blk * CHUNK, e1 = min(e0 + CHUNK, NE);
    for (int e = e0 + tid; e < e1; e += 256) atomicAdd(&cnt[dd[e] >> 8], 1);
    __syncthreads();
    if (tid < NB) base[tid] = cnt[tid] ? atomicAdd(&bucketCur[r * NB + tid], cnt[tid]) : 0;
    __syncthreads();
    for (int e = e0 + tid; e < e1; e += 256) {
        int d = dd[e], b = d >> 8;
        int rank = atomicAdd(&cur[b], 1);
        pairs[(size_t)(r * NB + b) * CAP + base[b] + rank] = make_int2(ss[e], d);
    }
}

// per-bucket fine CSR into fixed-capacity perm regions
__global__ __launch_bounds__(256) void csr_kernel(
        const int2* __restrict__ pairs, const int* __restrict__ bucketCur,
        int* __restrict__ offs, int* __restrict__ cnts, int* __restrict__ perm) {
    __shared__ int hist[256], sc[256], cur[256];
    int bx = blockIdx.x;
    int r = bx / NB, b = bx % NB;
    int tid = threadIdx.x;
    int nE = bucketCur[r * NB + b];
    size_t region = (size_t)(r * NB + b) * CAP;
    const int2* pr = pairs + region;
    hist[tid] = 0;
    __syncthreads();
    for (int i = tid; i < nE; i += 256) atomicAdd(&hist[pr[i].y & 255], 1);
    __syncthreads();
    int v = hist[tid];
    sc[tid] = v;
    __syncthreads();
    for (int off = 1; off < 256; off <<= 1) {
        int t = tid >= off ? sc[tid - off] : 0;
        __syncthreads();
        sc[tid] += t;
        __syncthreads();
    }
    int excl = sc[tid] - v;
    int dstg = b * 256 + tid;
    if (dstg < N_DST) { offs[r * N_DST + dstg] = (int)region + excl; cnts[r * N_DST + dstg] = v; }
    cur[tid] = excl;
    __syncthreads();
    int* pm = perm + region;
    for (int i = tid; i < nE; i += 256) {
        int2 p = pr[i];
        int rank = atomicAdd(&cur[p.y & 255], 1);
        pm[rank] = p.x;
    }
}

// ---------------------------------------------------------------------------
// split-bf16 MFMA GEMM with LDS-staged fragment-linear B (unchanged from r2).
__global__ __launch_bounds__(512) void gemm_er_kernel(
        const float* __restrict__ A0, const float* __restrict__ A1, const float* __restrict__ A2,
        const ushort_t* __restrict__ Bv,
        const float* __restrict__ al0, const float* __restrict__ al1, const float* __restrict__ al2,
        const float* __restrict__ dstf, const float* __restrict__ wv,
        ushort_t* __restrict__ hs, float* __restrict__ elv) {
    __shared__ ushort_t Bs[32768];                 // 64KB; epilogue reuses as Csh
    int bx = blockIdx.x;
    int rel = bx / GEMM_BLKS, blk = bx % GEMM_BLKS;
    const float* A  = rel == 0 ? A0 : (rel == 1 ? A1 : A2);
    const float* al = rel == 0 ? al0 : (rel == 1 ? al1 : al2);
    ushort_t* C = hs + (size_t)rel * N_SRC * 128;
    int tid = threadIdx.x;

    // --- stage B: linear 64KB copy, coalesced ---
    {
        const uint4* src = (const uint4*)(Bv + (size_t)rel * 32768);
        uint4* dl = (uint4*)Bs;
        #pragma unroll
        for (int i = 0; i < 8; i++) dl[tid + i * 512] = src[tid + i * 512];
    }

    int w = tid >> 6, lane = tid & 63;
    int quad = lane >> 4, l15 = lane & 15;
    int row0 = blk * 256 + w * 32;                 // wave's 32 rows

    int gr0 = row0 + l15;      if (gr0 > N_SRC - 1) gr0 = N_SRC - 1;
    int gr1 = row0 + 16 + l15; if (gr1 > N_SRC - 1) gr1 = N_SRC - 1;
    const float* a0p = A + (size_t)gr0 * 128 + quad * 8;
    const float* a1p = A + (size_t)gr1 * 128 + quad * 8;

    float4 abuf[2][2][2];
    abuf[0][0][0] = *(const float4*)(a0p + 0);
    abuf[0][0][1] = *(const float4*)(a0p + 4);
    abuf[0][1][0] = *(const float4*)(a1p + 0);
    abuf[0][1][1] = *(const float4*)(a1p + 4);

    __syncthreads();                               // B staged

    f32x4 acc[2][8] = {};
    #pragma unroll
    for (int kc = 0; kc < 4; kc++) {
        const int par = kc & 1;
        if (kc < 3) {                              // prefetch next kc
            int ko = (kc + 1) * 32;
            abuf[par ^ 1][0][0] = *(const float4*)(a0p + ko);
            abuf[par ^ 1][0][1] = *(const float4*)(a0p + ko + 4);
            abuf[par ^ 1][1][0] = *(const float4*)(a1p + ko);
            abuf[par ^ 1][1][1] = *(const float4*)(a1p + ko + 4);
        }
        bf16x8 ah[2], alo[2];
        #pragma unroll
        for (int t = 0; t < 2; t++)
            cvt8(abuf[par][t][0], abuf[par][t][1], ah[t], alo[t]);

        #pragma unroll
        for (int h2 = 0; h2 < 2; h2++) {
            #pragma unroll
            for (int n4 = 0; n4 < 4; n4++) {
                int f = kc * 16 + h2 * 8 + n4;     // hi frag; lo = f+4
                bf16x8 bh = *(const bf16x8*)&Bs[f * 512 + lane * 8];
                bf16x8 bl = *(const bf16x8*)&Bs[(f + 4) * 512 + lane * 8];
                int nt = h2 * 4 + n4;
                #pragma unroll
                for (int t = 0; t < 2; t++) {
                    acc[t][nt] = __builtin_amdgcn_mfma_f32_16x16x32_bf16(ah[t],  bh, acc[t][nt], 0, 0, 0);
                    acc[t][nt] = __builtin_amdgcn_mfma_f32_16x16x32_bf16(alo[t], bh, acc[t][nt], 0, 0, 0);
                    acc[t][nt] = __builtin_amdgcn_mfma_f32_16x16x32_bf16(ah[t],  bl, acc[t][nt], 0, 0, 0);
                }
            }
        }
    }

    // el epilogue
    float alv[8];
    #pragma unroll
    for (int nt = 0; nt < 8; nt++) alv[nt] = al[nt * 16 + l15];
    #pragma unroll
    for (int t = 0; t < 2; t++) {
        float part[4] = {0.f, 0.f, 0.f, 0.f};
        #pragma unroll
        for (int nt = 0; nt < 8; nt++)
            #pragma unroll
            for (int i = 0; i < 4; i++)
                part[i] = fmaf(acc[t][nt][i], alv[nt], part[i]);
        #pragma unroll
        for (int msk = 1; msk < 16; msk <<= 1)
            #pragma unroll
            for (int i = 0; i < 4; i++) part[i] += __shfl_xor(part[i], msk);
        if (l15 == 0) {
            #pragma unroll
            for (int i = 0; i < 4; i++) {
                int gr = row0 + t * 16 + quad * 4 + i;
                if (gr < N_SRC) elv[rel * N_DST + gr] = part[i];
            }
        }
    }

    // er tail loads issued early: latency hides under the C epilogue.
    int erbase = bx * ER_PB;
    float m0[11], m1[11];
    float wl0 = 0.f, wh0 = 0.f, wl1 = 0.f, wh1 = 0.f, wl2 = 0.f, wh2 = 0.f;
    int rend = 0;
    if (erbase < N_DST) {
        rend = min(erbase + ER_PB, N_DST);
        wl0 = wv[lane];       wh0 = wv[lane + 64];
        wl1 = wv[128 + lane]; wh1 = wv[128 + lane + 64];
        wl2 = wv[256 + lane]; wh2 = wv[256 + lane + 64];
        #pragma unroll
        for (int j = 0; j < 11; j++) {
            int r = erbase + w + 8 * j;
            int rr = r < rend ? r : erbase;
            m0[j] = dstf[(size_t)rr * 128 + lane];
            m1[j] = dstf[(size_t)rr * 128 + lane + 64];
        }
    }

    __syncthreads();                               // all waves done reading Bs

    // C epilogue: bf16 transpose through wave-private LDS slice of Bs
    ushort_t* Csh = Bs + w * 2304;                 // [32][72]
    #pragma unroll
    for (int h = 0; h < 2; h++) {
        __asm__ __volatile__("" ::: "memory");
        #pragma unroll
        for (int t = 0; t < 2; t++)
            #pragma unroll
            for (int ntl = 0; ntl < 4; ntl++) {
                int nt = h * 4 + ntl;
                #pragma unroll
                for (int i = 0; i < 4; i++)
                    Csh[(t * 16 + quad * 4 + i) * 72 + ntl * 16 + l15] = f2bf(acc[t][nt][i]);
            }
        __asm__ __volatile__("" ::: "memory");
        int r2 = lane >> 1, cb = (lane & 1) * 32;
        int gr = row0 + r2;
        if (gr < N_SRC) {
            ushort_t* dst = C + (size_t)gr * 128 + h * 64 + cb;
            #pragma unroll
            for (int k2 = 0; k2 < 4; k2++) {
                uint4 v = *(const uint4*)&Csh[r2 * 72 + cb + k2 * 8];
                *(uint4*)(dst + k2 * 8) = v;
            }
        }
    }

    // er tail compute
    if (erbase < N_DST) {
        #pragma unroll
        for (int j = 0; j < 11; j++) {
            int r = erbase + w + 8 * j;
            if (r < rend) {
                float p0 = fmaf(m0[j], wl0, m1[j] * wh0);
                float p1 = fmaf(m0[j], wl1, m1[j] * wh1);
                float p2 = fmaf(m0[j], wl2, m1[j] * wh2);
                #pragma unroll
                for (int off = 32; off > 0; off >>= 1) {
                    p0 += __shfl_down(p0, off);
                    p1 += __shfl_down(p1, off);
                    p2 += __shfl_down(p2, off);
                }
                if (lane == 0) {
                    elv[3 * N_DST + r] = p0;
                    elv[4 * N_DST + r] = p1;
                    elv[5 * N_DST + r] = p2;
                }
            }
        }
    }
}

// ---------------------------------------------------------------------------
// edge softmax + aggregation: half-wave (32 lanes) per dst, 8 dsts/block.
// Round-5: STRAIGHT-LINE batched fast path (deg<=32, ~99.99%) with a
// sched_barrier(0) fence. Round-4's batching was re-serialized by the
// register-minimizing scheduler (VGPR=40 proved only 1-2 rows in flight).
// Fix:
//   - el[s0] load issued FIRST (vmcnt retires in order: issuing it before
//     the 16 row loads lets its wait be vmcnt(16), overlapping the rows).
//   - all 16 row loads (edges 0..31, dummies hit L1-hot row 0) issued
//     unconditionally in straight-line code — no branch between issue and
//     use for MachineSink to exploit.
//   - __builtin_amdgcn_sched_barrier(0) pins loads above the softmax/FMA.
// Expected: VGPR ~100-130, ~2 memory round trips per dst.
__global__ __launch_bounds__(256) void aggregate_kernel(
        const ushort_t* __restrict__ hs, const float* __restrict__ elv,
        const int* __restrict__ perm, const int* __restrict__ offs,
        const int* __restrict__ cnts,
        const float* __restrict__ bg0, const float* __restrict__ bg1,
        const float* __restrict__ bg2, float* __restrict__ zm) {
    int tid = threadIdx.x;
    int wave = tid >> 6, lane = tid & 63;
    int hw = lane >> 5, l31 = lane & 31;
    int bx  = blockIdx.x;
    int rel = bx / 6250;
    int b   = (bx % 6250) * 8 + wave * 2 + hw;
    const float* el  = elv + rel * N_DST;
    float erb = elv[(3 + rel) * N_DST + b];
    const float* bg = rel == 0 ? bg0 : (rel == 1 ? bg1 : bg2);
    const ushort_t* hsr = hs + (size_t)rel * N_SRC * 128;
    int o0 = offs[rel * N_DST + b], deg = cnts[rel * N_DST + b];
    float* zout = zm + ((size_t)b * 3 + rel) * 128;

    if (deg <= 32) {
        int s0 = 0;
        if (l31 < deg) s0 = perm[o0 + l31];
        // scattered el load issued before the row loads (in-order vmcnt:
        // its wait then leaves the 16 row loads in flight).
        float xel = el[s0];

        int sub = l31 >> 4;                   // 16-lane subgroup: one 256B row
        int col16 = (l31 & 15) * 16;
        const char* basep = (const char*)hsr;

        // distribute all 32 edge src-ids, issue all 16 row loads
        int sv[8], sv2[8];
        #pragma unroll
        for (int i = 0; i < 8; i++) sv[i]  = __shfl(s0, 2 * i + sub, 32);
        #pragma unroll
        for (int i = 0; i < 8; i++) sv2[i] = __shfl(s0, 16 + 2 * i + sub, 32);
        uint4 h[8], h2[8];
        #pragma unroll
        for (int i = 0; i < 8; i++)
            h[i]  = *(const uint4*)(basep + (unsigned)(sv[i] * 256 + col16));
        #pragma unroll
        for (int i = 0; i < 8; i++)
            h2[i] = *(const uint4*)(basep + (unsigned)(sv2[i] * 256 + col16));
        __builtin_amdgcn_sched_barrier(0);    // loads stay above this line

        // softmax denominator (no max-subtraction: |x| small, validated)
        float x = xel + erb;
        x = x >= 0.f ? x : NEG_SLOPE * x;
        float e0 = (l31 < deg) ? __expf(x) : 0.f;
        float lsum = e0;
        #pragma unroll
        for (int msk = 1; msk < 32; msk <<= 1) lsum += __shfl_xor(lsum, msk);
        float invz = deg > 0 ? 1.f / lsum : 0.f;

        float wt[8], wt2[8];
        #pragma unroll
        for (int i = 0; i < 8; i++) wt[i]  = __shfl(e0, 2 * i + sub, 32);
        #pragma unroll
        for (int i = 0; i < 8; i++) wt2[i] = __shfl(e0, 16 + 2 * i + sub, 32);

        float a0 = 0.f, a1 = 0.f, a2 = 0.f, a3 = 0.f;
        float a4 = 0.f, a5 = 0.f, a6 = 0.f, a7 = 0.f;
        #pragma unroll
        for (int i = 0; i < 8; i++) {
            float e_ = wt[i];
            a0 = fmaf(e_, bflo(h[i].x), a0); a1 = fmaf(e_, bfhi(h[i].x), a1);
            a2 = fmaf(e_, bflo(h[i].y), a2); a3 = fmaf(e_, bfhi(h[i].y), a3);
            a4 = fmaf(e_, bflo(h[i].z), a4); a5 = fmaf(e_, bfhi(h[i].z), a5);
            a6 = fmaf(e_, bflo(h[i].w), a6); a7 = fmaf(e_, bfhi(h[i].w), a7);
        }
        #pragma unroll
        for (int i = 0; i < 8; i++) {
            float e_ = wt2[i];
            a0 = fmaf(e_, bflo(h2[i].x), a0); a1 = fmaf(e_, bfhi(h2[i].x), a1);
            a2 = fmaf(e_, bflo(h2[i].y), a2); a3 = fmaf(e_, bfhi(h2[i].y), a3);
            a4 = fmaf(e_, bflo(h2[i].z), a4); a5 = fmaf(e_, bfhi(h2[i].z), a5);
            a6 = fmaf(e_, bflo(h2[i].w), a6); a7 = fmaf(e_, bfhi(h2[i].w), a7);
        }

        // combine the two 16-lane subgroups (even + odd edges)
        a0 += __shfl_xor(a0, 16); a1 += __shfl_xor(a1, 16);
        a2 += __shfl_xor(a2, 16); a3 += __shfl_xor(a3, 16);
        a4 += __shfl_xor(a4, 16); a5 += __shfl_xor(a5, 16);
        a6 += __shfl_xor(a6, 16); a7 += __shfl_xor(a7, 16);

        if (sub == 0) {
            int c = (l31 & 15) * 8;
            float4 bgv0 = *(const float4*)&bg[c];
            float4 bgv1 = *(const float4*)&bg[c + 4];
            float4 z0, z1;
            z0.x = fmaf(a0, invz, bgv0.x); z0.y = fmaf(a1, invz, bgv0.y);
            z0.z = fmaf(a2, invz, bgv0.z); z0.w = fmaf(a3, invz, bgv0.w);
            z1.x = fmaf(a4, invz, bgv1.x); z1.y = fmaf(a5, invz, bgv1.y);
            z1.z = fmaf(a6, invz, bgv1.z); z1.w = fmaf(a7, invz, bgv1.w);
            z0.x = z0.x > 0.f ? z0.x : __expf(z0.x) - 1.f;
            z0.y = z0.y > 0.f ? z0.y : __expf(z0.y) - 1.f;
            z0.z = z0.z > 0.f ? z0.z : __expf(z0.z) - 1.f;
            z0.w = z0.w > 0.f ? z0.w : __expf(z0.w) - 1.f;
            z1.x = z1.x > 0.f ? z1.x : __expf(z1.x) - 1.f;
            z1.y = z1.y > 0.f ? z1.y : __expf(z1.y) - 1.f;
            z1.z = z1.z > 0.f ? z1.z : __expf(z1.z) - 1.f;
            z1.w = z1.w > 0.f ? z1.w : __expf(z1.w) - 1.f;
            *(float4*)&zout[c] = z0;
            *(float4*)&zout[c + 4] = z1;
        }
    } else {
        // rare (P(deg>32)≈1e-4): 32-lane strided generic path, with max
        float lmax = -INFINITY;
        for (int i = l31; i < deg; i += 32) {
            int s = perm[o0 + i];
            float x = el[s] + erb;
            x = x >= 0.f ? x : NEG_SLOPE * x;
            lmax = fmaxf(lmax, x);
        }
        #pragma unroll
        for (int msk = 1; msk < 32; msk <<= 1) lmax = fmaxf(lmax, __shfl_xor(lmax, msk));
        float lsum = 0.f;
        for (int i = l31; i < deg; i += 32) {
            int s = perm[o0 + i];
            float x = el[s] + erb;
            x = x >= 0.f ? x : NEG_SLOPE * x;
            lsum += __expf(x - lmax);
        }
        #pragma unroll
        for (int msk = 1; msk < 32; msk <<= 1) lsum += __shfl_xor(lsum, msk);
        float invz = 1.f / lsum;
        float c0 = 0.f, c1 = 0.f, c2 = 0.f, c3 = 0.f;
        for (int j = 0; j < deg; j++) {
            int s = perm[o0 + j];
            float x = el[s] + erb;
            x = x >= 0.f ? x : NEG_SLOPE * x;
            float e_ = __expf(x - lmax) * invz;
            uint2 hv = *(const uint2*)(hsr + (size_t)s * 128 + l31 * 4);
            c0 = fmaf(e_, bflo(hv.x), c0);
            c1 = fmaf(e_, bfhi(hv.x), c1);
            c2 = fmaf(e_, bflo(hv.y), c2);
            c3 = fmaf(e_, bfhi(hv.y), c3);
        }
        int c = l31 * 4;
        float4 bgv = *(const float4*)&bg[c];
        float4 z;
        z.x = c0 + bgv.x; z.y = c1 + bgv.y;
        z.z = c2 + bgv.z; z.w = c3 + bgv.w;
        z.x = z.x > 0.f ? z.x : __expf(z.x) - 1.f;
        z.y = z.y > 0.f ? z.y : __expf(z.y) - 1.f;
        z.z = z.z > 0.f ? z.z : __expf(z.z) - 1.f;
        z.w = z.w > 0.f ? z.w : __expf(z.w) - 1.f;
        *(float4*)&zout[c] = z;
    }
}

// ---------------------------------------------------------------------------
// semantic attention via bf16 MFMA — persistent grid-stride (Wt staged once).
__global__ __launch_bounds__(256) void semantic_kernel(
        const float* __restrict__ zm, const ushort_t* __restrict__ Wt_g,
        const float* __restrict__ b1, const float* __restrict__ W2,
        float* __restrict__ w_sum) {
    __shared__ ushort_t Wt[128 * 136];
    __shared__ float hsum[3];
    const int NROWS = N_DST * 3;
    int tid = threadIdx.x;
    if (tid < 3) hsum[tid] = 0.f;

    #pragma unroll
    for (int i = 0; i < 8; i++) {
        int c = i * 256 + tid;
        int n = c >> 4, c16 = c & 15;
        uint4 t = *(const uint4*)(Wt_g + n * 128 + c16 * 8);
        *(uint4*)&Wt[n * 136 + c16 * 8] = t;
    }
    __syncthreads();

    int w    = tid >> 6, lane = tid & 63;
    int quad = lane >> 4, l15 = lane & 15;

    for (int tile = blockIdx.x; tile < SEM_TILES; tile += gridDim.x) {
        long row0 = (long)tile * 64 + w * 16;
        long rA = row0 + l15; if (rA > NROWS - 1) rA = NROWS - 1;

        f32x4 acc[8] = {};
        #pragma unroll
        for (int kc = 0; kc < 4; kc++) {
            int k0 = kc * 32 + quad * 8;
            const float* src = zm + (size_t)rA * 128 + k0;
            float4 f0 = *(const float4*)src;
            float4 f1 = *(const float4*)(src + 4);
            bf16x8 a;
            a[0] = (short)f2bf(f0.x); a[1] = (short)f2bf(f0.y);
            a[2] = (short)f2bf(f0.z); a[3] = (short)f2bf(f0.w);
            a[4] = (short)f2bf(f1.x); a[5] = (short)f2bf(f1.y);
            a[6] = (short)f2bf(f1.z); a[7] = (short)f2bf(f1.w);
            #pragma unroll
            for (int nt = 0; nt < 8; nt++) {
                int n = nt * 16 + l15;
                bf16x8 bfr = *(const bf16x8*)&Wt[n * 136 + k0];
                acc[nt] = __builtin_amdgcn_mfma_f32_16x16x32_bf16(a, bfr, acc[nt], 0, 0, 0);
            }
        }

        float part[4] = {0.f, 0.f, 0.f, 0.f};
        #pragma unroll
        for (int nt = 0; nt < 8; nt++) {
            int n = nt * 16 + l15;
            float bbn = b1[n], ww = W2[n];
            #pragma unroll
            for (int i = 0; i < 4; i++) {
                float t = tanh_fast(acc[nt][i] + bbn);
                part[i] = fmaf(t, ww, part[i]);
            }
        }
        #pragma unroll
        for (int msk = 1; msk < 16; msk <<= 1)
            #pragma unroll
            for (int i = 0; i < 4; i++) part[i] += __shfl_xor(part[i], msk);
        if (l15 == 0) {
            #pragma unroll
            for (int i = 0; i < 4; i++) {
                long R = row0 + quad * 4 + i;
                if (R < NROWS) atomicAdd(&hsum[(int)(R % 3)], part[i]);
            }
        }
    }
    __syncthreads();
    if (tid < 3) atomicAdd(&w_sum[tid], hsum[tid]);
}

// ---------------------------------------------------------------------------
__global__ void combine_kernel(const float* __restrict__ zm, const float* __restrict__ w_sum,
                               float* __restrict__ out, float* __restrict__ out_att) {
    float w0 = w_sum[0] * (1.f / (float)N_DST);
    float w1 = w_sum[1] * (1.f / (float)N_DST);
    float w2 = w_sum[2] * (1.f / (float)N_DST);
    float m = fmaxf(w0, fmaxf(w1, w2));
    float e0 = __expf(w0 - m), e1 = __expf(w1 - m), e2 = __expf(w2 - m);
    float s = 1.f / (e0 + e1 + e2);
    float a0 = e0 * s, a1 = e1 * s, a2 = e2 * s;
    if (blockIdx.x == 0 && threadIdx.x < 3)
        out_att[threadIdx.x] = threadIdx.x == 0 ? a0 : (threadIdx.x == 1 ? a1 : a2);
    int id4 = blockIdx.x * 256 + threadIdx.x;
    int n  = id4 >> 5;
    int d4 = (id4 & 31) * 4;
    const float4 z0 = *(const float4*)&zm[((size_t)n * 3 + 0) * 128 + d4];
    const float4 z1 = *(const float4*)&zm[((size_t)n * 3 + 1) * 128 + d4];
    const float4 z2 = *(const float4*)&zm[((size_t)n * 3 + 2) * 128 + d4];
    float4 o;
    o.x = a0 * z0.x + a1 * z1.x + a2 * z2.x;
    o.y = a0 * z0.y + a1 * z1.y + a2 * z2.y;
    o.z = a0 * z0.z + a1 * z1.z + a2 * z2.z;
    o.w = a0 * z0.w + a1 * z1.w + a2 * z2.w;
    *(float4*)&out[(size_t)n * 128 + d4] = o;
}

// ---------------------------------------------------------------------------
extern "C" void kernel_launch(void* const* d_in, const int* in_sizes, int n_in,
                              void* d_out, int out_size, void* d_ws, size_t ws_size,
                              hipStream_t stream) {
    const float* dstf   = (const float*)d_in[0];
    const float* src0   = (const float*)d_in[1];
    const float* src1   = (const float*)d_in[2];
    const float* src2   = (const float*)d_in[3];
    const float* sem_W1 = (const float*)d_in[4];
    const float* sem_b1 = (const float*)d_in[5];
    const float* sem_W2 = (const float*)d_in[6];
    const float* Wg[3]  = {(const float*)d_in[7],  (const float*)d_in[13], (const float*)d_in[19]};
    const float* al[3]  = {(const float*)d_in[8],  (const float*)d_in[14], (const float*)d_in[20]};
    const float* ar[3]  = {(const float*)d_in[9],  (const float*)d_in[15], (const float*)d_in[21]};
    const float* bg[3]  = {(const float*)d_in[10], (const float*)d_in[16], (const float*)d_in[22]};
    const int*  sidx[3] = {(const int*)d_in[11], (const int*)d_in[17], (const int*)d_in[23]};
    const int*  didx[3] = {(const int*)d_in[12], (const int*)d_in[18], (const int*)d_in[24]};
    float* out = (float*)d_out;

    char* p = (char*)d_ws;
    auto alloc = [&](size_t bytes) -> char* {
        char* q = p; p += (bytes + 255) & ~(size_t)255; return q;
    };
    float*    zm   = (float*)alloc((size_t)N_DST * 3 * 128 * 4);    // 76.8 MB (pairs aliases)
    ushort_t* hs   = (ushort_t*)alloc((size_t)3 * N_SRC * 128 * 2); // 38.4 MB bf16
    float*    elv  = (float*)alloc((size_t)6 * N_DST * 4);
    float*    wv   = (float*)alloc((size_t)3 * 128 * 4);
    ushort_t* Wt_g = (ushort_t*)alloc((size_t)128 * 128 * 2);
    ushort_t* Bv   = (ushort_t*)alloc((size_t)3 * 32768 * 2);       // fragment-linear B
    int* cnts = (int*)alloc((size_t)3 * N_DST * 4);
    int* offs = (int*)alloc((size_t)3 * N_DST * 4);
    int* perm = (int*)alloc((size_t)3 * NB * CAP * 4);              // 10.8 MB
    int* zero = (int*)alloc((size_t)(3 * NB + 8) * 4);              // bucketCur + wsum
    int*   bucketCur = zero;
    float* wsum      = (float*)(zero + 3 * NB);
    int2* pairs = (int2*)zm;    // 21.7 MB alias; dead before aggregate writes zm

    hipMemsetAsync(zero, 0, (size_t)(3 * NB + 8) * 4, stream);

    vecprep_kernel<<<259, 256, 0, stream>>>(Wg[0], Wg[1], Wg[2], ar[0], ar[1], ar[2],
                                            sem_W1, wv, Wt_g, Bv);
    bucket_scatter_kernel<<<3 * NBLK_REL, 256, 0, stream>>>(didx[0], didx[1], didx[2],
                                                            sidx[0], sidx[1], sidx[2],
                                                            bucketCur, pairs);
    csr_kernel<<<3 * NB, 256, 0, stream>>>(pairs, bucketCur, offs, cnts, perm);
    gemm_er_kernel<<<GEMM_GRID, 512, 0, stream>>>(src0, src1, src2, Bv,
                                                  al[0], al[1], al[2],
                                                  dstf, wv, hs, elv);
    aggregate_kernel<<<3 * 6250, 256, 0, stream>>>(hs, elv, perm, offs, cnts,
                                                   bg[0], bg[1], bg[2], zm);
    semantic_kernel<<<SEM_GRID, 256, 0, stream>>>(zm, Wt_g, sem_b1, sem_W2, wsum);
    combine_kernel<<<6250, 256, 0, stream>>>(zm, wsum, out, out + (size_t)N_DST * 128);
}

// Round 6
// 397.156 us; speedup vs baseline: 1.0642x; 1.0642x over previous
//
#include <hip/hip_runtime.h>
#include <math.h>

#define D_DIM 128
#define N_DST 50000
#define N_SRC 50000
#define NE    800000
#define NEG_SLOPE 0.2f

#define NB        196      // coarse buckets: dst>>8
#define CAP       4608     // fixed bucket capacity (λ=4082, +8.2σ)
#define CHUNK     8192
#define NBLK_REL  98       // ceil(NE / CHUNK)
#define GEMM_BLKS 196      // 256 rows/block (8 waves × 32 rows)
#define GEMM_GRID (3 * GEMM_BLKS)   // 588
#define CSR_GRID  (3 * NB)          // 588
#define ER_PB     86       // er rows per gemm block: 588 * 86 = 50568 >= 50000
#define SEM_GRID  512      // persistent semantic blocks
#define SEM_TILES ((3 * N_DST + 63) / 64)

typedef unsigned short ushort_t;
using f32x4  = __attribute__((ext_vector_type(4))) float;
using bf16x8 = __attribute__((ext_vector_type(8))) short;

__device__ __forceinline__ ushort_t f2bf(float x) {
    unsigned u = __float_as_uint(x);
    unsigned r = (u + 0x7fffu + ((u >> 16) & 1u)) >> 16;
    return (ushort_t)r;
}
__device__ __forceinline__ float bf2f(ushort_t b) {
    return __uint_as_float(((unsigned)b) << 16);
}
__device__ __forceinline__ float bflo(unsigned u) { return __uint_as_float(u << 16); }
__device__ __forceinline__ float bfhi(unsigned u) { return __uint_as_float(u & 0xffff0000u); }
__device__ __forceinline__ float tanh_fast(float x) {
    float e = __expf(2.f * x);
    return 1.f - 2.f / (e + 1.f);
}

// convert 8 fp32 -> split bf16 (hi round-nearest-even, lo truncated)
__device__ __forceinline__ void cvt8(float4 f0, float4 f1, bf16x8& hi, bf16x8& lo) {
    float f[8] = {f0.x, f0.y, f0.z, f0.w, f1.x, f1.y, f1.z, f1.w};
    #pragma unroll
    for (int i = 0; i < 8; i++) {
        ushort_t h = f2bf(f[i]);
        hi[i] = (short)h;
        lo[i] = (short)(ushort_t)(__float_as_uint(f[i] - bf2f(h)) >> 16);
    }
}

// ---------------------------------------------------------------------------
// K1 = vecprep ∪ bucket_scatter (independent work, one launch).
//   bx < 259: merged prep ([0,3) wv_r ; [3,67) W1^T -> Wt_g ; [67,259) Bv)
//   bx >= 259: bucket scatter (294 blocks)
__global__ __launch_bounds__(256) void prep_scatter_kernel(
        const float* __restrict__ Wg0, const float* __restrict__ Wg1,
        const float* __restrict__ Wg2,
        const float* __restrict__ ar0, const float* __restrict__ ar1,
        const float* __restrict__ ar2,
        const float* __restrict__ W1,
        float* __restrict__ wv, ushort_t* __restrict__ Wt_g,
        ushort_t* __restrict__ Bv,
        const int* __restrict__ d0, const int* __restrict__ d1, const int* __restrict__ d2,
        const int* __restrict__ s0, const int* __restrict__ s1, const int* __restrict__ s2,
        int* __restrict__ bucketCur, int2* __restrict__ pairs) {
    __shared__ int cnt[NB], base[NB], cur[NB];
    int bx = blockIdx.x, tid = threadIdx.x;
    if (bx < 259) {
        if (bx < 3) {
            if (tid < 128) {
                const float* W  = bx == 0 ? Wg0 : (bx == 1 ? Wg1 : Wg2);
                const float* ar = bx == 0 ? ar0 : (bx == 1 ? ar1 : ar2);
                float sar = 0.f;
                for (int j = 0; j < D_DIM; j++) sar = fmaf(W[tid * D_DIM + j], ar[j], sar);
                wv[bx * D_DIM + tid] = sar;
            }
        } else if (bx < 67) {
            int idx = (bx - 3) * 256 + tid;           // 16384
            int k = idx >> 7, n = idx & 127;
            Wt_g[n * 128 + k] = f2bf(W1[idx]);
        } else {
            int q = bx - 67;
            int rel = q >> 6;
            int idx = (q & 63) * 256 + tid;           // 16384 per rel
            const float* W = rel == 0 ? Wg0 : (rel == 1 ? Wg1 : Wg2);
            int k = idx >> 7, n = idx & 127;          // value = Wg[k][n] = B^T[n][k]
            float v = W[idx];
            ushort_t hi = f2bf(v);
            ushort_t lo = f2bf(v - bf2f(hi));
            int nt = n >> 4, l15 = n & 15;
            int kc = k >> 5, quad = (k >> 3) & 3, e = k & 7;
            int h2 = nt >> 2, n4 = nt & 3;
            int lane = quad * 16 + l15;
            int fh = kc * 16 + h2 * 8 + n4;           // hl=0
            ushort_t* dst = Bv + (size_t)rel * 32768;
            dst[(fh)     * 512 + lane * 8 + e] = hi;
            dst[(fh + 4) * 512 + lane * 8 + e] = lo;  // hl=1 → +4 frags
        }
        return;
    }
    // ---- bucket scatter ----
    int sb = bx - 259;
    int r = sb / NBLK_REL, blk = sb % NBLK_REL;
    const int* dd = r == 0 ? d0 : (r == 1 ? d1 : d2);
    const int* ss = r == 0 ? s0 : (r == 1 ? s1 : s2);
    if (tid < NB) { cnt[tid] = 0; cur[tid] = 0; }
    __syncthreads();
    int e0 = blk * CHUNK, e1 = min(e0 + CHUNK, NE);
    for (int e = e0 + tid; e < e1; e += 256) atomicAdd(&cnt[dd[e] >> 8], 1);
    __syncthreads();
    if (tid < NB) base[tid] = cnt[tid] ? atomicAdd(&bucketCur[r * NB + tid], cnt[tid]) : 0;
    __syncthreads();
    for (int e = e0 + tid; e < e1; e += 256) {
        int d = dd[e], b = d >> 8;
        int rank = atomicAdd(&cur[b], 1);
        pairs[(size_t)(r * NB + b) * CAP + base[b] + rank] = make_int2(ss[e], d);
    }
}

// ---------------------------------------------------------------------------
// K2 = gemm_er ∪ csr (both depend only on K1; csr's scan/atomic work overlaps
// gemm's MFMA/BW on co-resident blocks). 512-thread blocks; csr part uses
// non-divergent barriers with tid<256 guards on the scan.
__global__ __launch_bounds__(512) void csr_gemm_kernel(
        const float* __restrict__ A0, const float* __restrict__ A1, const float* __restrict__ A2,
        const ushort_t* __restrict__ Bv,
        const float* __restrict__ al0, const float* __restrict__ al1, const float* __restrict__ al2,
        const float* __restrict__ dstf, const float* __restrict__ wv,
        ushort_t* __restrict__ hs, float* __restrict__ elv,
        const int2* __restrict__ pairs, const int* __restrict__ bucketCur,
        int* __restrict__ offs, int* __restrict__ cnts, int* __restrict__ perm) {
    __shared__ ushort_t Bs[32768];                 // 64KB; csr aliases; epilogue reuses
    int bx = blockIdx.x;
    int tid = threadIdx.x;

    if (bx >= GEMM_GRID) {
        // ---- csr part (512 threads, strided loops) ----
        int cb = bx - GEMM_GRID;
        int r = cb / NB, b = cb % NB;
        int* hist = (int*)Bs;                      // [256]
        int* sc   = hist + 256;                    // [256]
        int* curc = hist + 512;                    // [256]
        int nE = bucketCur[r * NB + b];
        size_t region = (size_t)(r * NB + b) * CAP;
        const int2* pr = pairs + region;
        if (tid < 256) hist[tid] = 0;
        __syncthreads();
        for (int i = tid; i < nE; i += 512) atomicAdd(&hist[pr[i].y & 255], 1);
        __syncthreads();
        int v = 0;
        if (tid < 256) { v = hist[tid]; sc[tid] = v; }
        __syncthreads();
        for (int off = 1; off < 256; off <<= 1) {
            int t = (tid < 256 && tid >= off) ? sc[tid - off] : 0;
            __syncthreads();
            if (tid < 256) sc[tid] += t;
            __syncthreads();
        }
        if (tid < 256) {
            int excl = sc[tid] - v;
            int dstg = b * 256 + tid;
            if (dstg < N_DST) { offs[r * N_DST + dstg] = (int)region + excl; cnts[r * N_DST + dstg] = v; }
            curc[tid] = excl;
        }
        __syncthreads();
        int* pm = perm + region;
        for (int i = tid; i < nE; i += 512) {
            int2 p = pr[i];
            int rank = atomicAdd(&curc[p.y & 255], 1);
            pm[rank] = p.x;
        }
        return;
    }

    // ---- gemm part (unchanged from r2 structure) ----
    int rel = bx / GEMM_BLKS, blk = bx % GEMM_BLKS;
    const float* A  = rel == 0 ? A0 : (rel == 1 ? A1 : A2);
    const float* al = rel == 0 ? al0 : (rel == 1 ? al1 : al2);
    ushort_t* C = hs + (size_t)rel * N_SRC * 128;

    // stage B: linear 64KB copy, coalesced
    {
        const uint4* src = (const uint4*)(Bv + (size_t)rel * 32768);
        uint4* dl = (uint4*)Bs;
        #pragma unroll
        for (int i = 0; i < 8; i++) dl[tid + i * 512] = src[tid + i * 512];
    }

    int w = tid >> 6, lane = tid & 63;
    int quad = lane >> 4, l15 = lane & 15;
    int row0 = blk * 256 + w * 32;                 // wave's 32 rows

    int gr0 = row0 + l15;      if (gr0 > N_SRC - 1) gr0 = N_SRC - 1;
    int gr1 = row0 + 16 + l15; if (gr1 > N_SRC - 1) gr1 = N_SRC - 1;
    const float* a0p = A + (size_t)gr0 * 128 + quad * 8;
    const float* a1p = A + (size_t)gr1 * 128 + quad * 8;

    float4 abuf[2][2][2];
    abuf[0][0][0] = *(const float4*)(a0p + 0);
    abuf[0][0][1] = *(const float4*)(a0p + 4);
    abuf[0][1][0] = *(const float4*)(a1p + 0);
    abuf[0][1][1] = *(const float4*)(a1p + 4);

    __syncthreads();                               // B staged

    f32x4 acc[2][8] = {};
    #pragma unroll
    for (int kc = 0; kc < 4; kc++) {
        const int par = kc & 1;
        if (kc < 3) {                              // prefetch next kc
            int ko = (kc + 1) * 32;
            abuf[par ^ 1][0][0] = *(const float4*)(a0p + ko);
            abuf[par ^ 1][0][1] = *(const float4*)(a0p + ko + 4);
            abuf[par ^ 1][1][0] = *(const float4*)(a1p + ko);
            abuf[par ^ 1][1][1] = *(const float4*)(a1p + ko + 4);
        }
        bf16x8 ah[2], alo[2];
        #pragma unroll
        for (int t = 0; t < 2; t++)
            cvt8(abuf[par][t][0], abuf[par][t][1], ah[t], alo[t]);

        #pragma unroll
        for (int h2 = 0; h2 < 2; h2++) {
            #pragma unroll
            for (int n4 = 0; n4 < 4; n4++) {
                int f = kc * 16 + h2 * 8 + n4;     // hi frag; lo = f+4
                bf16x8 bh = *(const bf16x8*)&Bs[f * 512 + lane * 8];
                bf16x8 bl = *(const bf16x8*)&Bs[(f + 4) * 512 + lane * 8];
                int nt = h2 * 4 + n4;
                #pragma unroll
                for (int t = 0; t < 2; t++) {
                    acc[t][nt] = __builtin_amdgcn_mfma_f32_16x16x32_bf16(ah[t],  bh, acc[t][nt], 0, 0, 0);
                    acc[t][nt] = __builtin_amdgcn_mfma_f32_16x16x32_bf16(alo[t], bh, acc[t][nt], 0, 0, 0);
                    acc[t][nt] = __builtin_amdgcn_mfma_f32_16x16x32_bf16(ah[t],  bl, acc[t][nt], 0, 0, 0);
                }
            }
        }
    }

    // el epilogue
    float alv[8];
    #pragma unroll
    for (int nt = 0; nt < 8; nt++) alv[nt] = al[nt * 16 + l15];
    #pragma unroll
    for (int t = 0; t < 2; t++) {
        float part[4] = {0.f, 0.f, 0.f, 0.f};
        #pragma unroll
        for (int nt = 0; nt < 8; nt++)
            #pragma unroll
            for (int i = 0; i < 4; i++)
                part[i] = fmaf(acc[t][nt][i], alv[nt], part[i]);
        #pragma unroll
        for (int msk = 1; msk < 16; msk <<= 1)
            #pragma unroll
            for (int i = 0; i < 4; i++) part[i] += __shfl_xor(part[i], msk);
        if (l15 == 0) {
            #pragma unroll
            for (int i = 0; i < 4; i++) {
                int gr = row0 + t * 16 + quad * 4 + i;
                if (gr < N_SRC) elv[rel * N_DST + gr] = part[i];
            }
        }
    }

    // er tail loads issued early: latency hides under the C epilogue.
    int erbase = bx * ER_PB;
    float m0[11], m1[11];
    float wl0 = 0.f, wh0 = 0.f, wl1 = 0.f, wh1 = 0.f, wl2 = 0.f, wh2 = 0.f;
    int rend = 0;
    if (erbase < N_DST) {
        rend = min(erbase + ER_PB, N_DST);
        wl0 = wv[lane];       wh0 = wv[lane + 64];
        wl1 = wv[128 + lane]; wh1 = wv[128 + lane + 64];
        wl2 = wv[256 + lane]; wh2 = wv[256 + lane + 64];
        #pragma unroll
        for (int j = 0; j < 11; j++) {
            int r = erbase + w + 8 * j;
            int rr = r < rend ? r : erbase;
            m0[j] = dstf[(size_t)rr * 128 + lane];
            m1[j] = dstf[(size_t)rr * 128 + lane + 64];
        }
    }

    __syncthreads();                               // all waves done reading Bs

    // C epilogue: bf16 transpose through wave-private LDS slice of Bs
    ushort_t* Csh = Bs + w * 2304;                 // [32][72]
    #pragma unroll
    for (int h = 0; h < 2; h++) {
        __asm__ __volatile__("" ::: "memory");
        #pragma unroll
        for (int t = 0; t < 2; t++)
            #pragma unroll
            for (int ntl = 0; ntl < 4; ntl++) {
                int nt = h * 4 + ntl;
                #pragma unroll
                for (int i = 0; i < 4; i++)
                    Csh[(t * 16 + quad * 4 + i) * 72 + ntl * 16 + l15] = f2bf(acc[t][nt][i]);
            }
        __asm__ __volatile__("" ::: "memory");
        int r2 = lane >> 1, cb2 = (lane & 1) * 32;
        int gr = row0 + r2;
        if (gr < N_SRC) {
            ushort_t* dst = C + (size_t)gr * 128 + h * 64 + cb2;
            #pragma unroll
            for (int k2 = 0; k2 < 4; k2++) {
                uint4 v = *(const uint4*)&Csh[r2 * 72 + cb2 + k2 * 8];
                *(uint4*)(dst + k2 * 8) = v;
            }
        }
    }

    // er tail compute
    if (erbase < N_DST) {
        #pragma unroll
        for (int j = 0; j < 11; j++) {
            int r = erbase + w + 8 * j;
            if (r < rend) {
                float p0 = fmaf(m0[j], wl0, m1[j] * wh0);
                float p1 = fmaf(m0[j], wl1, m1[j] * wh1);
                float p2 = fmaf(m0[j], wl2, m1[j] * wh2);
                #pragma unroll
                for (int off = 32; off > 0; off >>= 1) {
                    p0 += __shfl_down(p0, off);
                    p1 += __shfl_down(p1, off);
                    p2 += __shfl_down(p2, off);
                }
                if (lane == 0) {
                    elv[3 * N_DST + r] = p0;
                    elv[4 * N_DST + r] = p1;
                    elv[5 * N_DST + r] = p2;
                }
            }
        }
    }
}

// ---------------------------------------------------------------------------
// edge softmax + aggregation — RESTORED to the round-3 version (84.6 µs,
// VGPR 20, occ 77%). Half-wave per dst, LDS ew stage, no max-subtraction on
// the deg<=64 path. Rounds 4-5 proved the shfl-batched register gather is
// re-serialized by the compiler (VGPR 40/60, occupancy collapse): occupancy
// beats per-wave MLP here. DO NOT re-attempt register batching.
__global__ __launch_bounds__(256) void aggregate_kernel(
        const ushort_t* __restrict__ hs, const float* __restrict__ elv,
        const int* __restrict__ perm, const int* __restrict__ offs,
        const int* __restrict__ cnts,
        const float* __restrict__ bg0, const float* __restrict__ bg1,
        const float* __restrict__ bg2, float* __restrict__ zm) {
    __shared__ int2 ew[4][2][64];
    int tid = threadIdx.x;
    int wave = tid >> 6, lane = tid & 63;
    int hw = lane >> 5, l31 = lane & 31;
    int bx  = blockIdx.x;
    int rel = bx / 6250;
    int b   = (bx % 6250) * 8 + wave * 2 + hw;
    const float* el  = elv + rel * N_DST;
    float erb = elv[(3 + rel) * N_DST + b];
    const float* bg = rel == 0 ? bg0 : (rel == 1 ? bg1 : bg2);
    const ushort_t* hsr = hs + (size_t)rel * N_SRC * 128;
    int o0 = offs[rel * N_DST + b], deg = cnts[rel * N_DST + b];
    float* zout = zm + ((size_t)b * 3 + rel) * 128;
    int2* ews = ew[wave][hw];

    if (deg <= 64) {
        // no max-subtraction: |leakyrelu(el+er)| small, exp safe in fp32
        int s0 = 0, s1 = 0;
        float e0 = 0.f, e1 = 0.f;
        if (l31 < deg) {
            s0 = perm[o0 + l31];
            float x = el[s0] + erb;
            x = x >= 0.f ? x : NEG_SLOPE * x;
            e0 = __expf(x);
        }
        if (deg > 32 && l31 + 32 < deg) {
            s1 = perm[o0 + l31 + 32];
            float x = el[s1] + erb;
            x = x >= 0.f ? x : NEG_SLOPE * x;
            e1 = __expf(x);
        }
        float lsum = e0 + e1;
        #pragma unroll
        for (int msk = 1; msk < 32; msk <<= 1) lsum += __shfl_xor(lsum, msk);
        float invz = deg > 0 ? 1.f / lsum : 0.f;

        ews[l31] = make_int2(s0 * 256, __float_as_int(e0 * invz));
        if (deg > 32)
            ews[l31 + 32] = make_int2(s1 * 256, __float_as_int(e1 * invz));
        __asm__ __volatile__("" ::: "memory");

        // gather: 4 rows / iter; 16 lanes × 16B cover each 256B row.
        int degp = (deg + 3) & ~3;
        const char* basep = (const char*)hsr;
        int sub = l31 >> 4;
        int col16 = (l31 & 15) * 16;
        float a0 = 0.f, a1 = 0.f, a2 = 0.f, a3 = 0.f;
        float a4 = 0.f, a5 = 0.f, a6 = 0.f, a7 = 0.f;
        for (int j = 0; j < degp; j += 4) {
            int2 pA = ews[j + sub];
            int2 pB = ews[j + 2 + sub];
            uint4 hA = *(const uint4*)(basep + (unsigned)(pA.x + col16));
            uint4 hB = *(const uint4*)(basep + (unsigned)(pB.x + col16));
            float eA = __int_as_float(pA.y), eB = __int_as_float(pB.y);
            a0 = fmaf(eA, bflo(hA.x), a0); a1 = fmaf(eA, bfhi(hA.x), a1);
            a2 = fmaf(eA, bflo(hA.y), a2); a3 = fmaf(eA, bfhi(hA.y), a3);
            a4 = fmaf(eA, bflo(hA.z), a4); a5 = fmaf(eA, bfhi(hA.z), a5);
            a6 = fmaf(eA, bflo(hA.w), a6); a7 = fmaf(eA, bfhi(hA.w), a7);
            a0 = fmaf(eB, bflo(hB.x), a0); a1 = fmaf(eB, bfhi(hB.x), a1);
            a2 = fmaf(eB, bflo(hB.y), a2); a3 = fmaf(eB, bfhi(hB.y), a3);
            a4 = fmaf(eB, bflo(hB.z), a4); a5 = fmaf(eB, bfhi(hB.z), a5);
            a6 = fmaf(eB, bflo(hB.w), a6); a7 = fmaf(eB, bfhi(hB.w), a7);
        }
        a0 += __shfl_xor(a0, 16); a1 += __shfl_xor(a1, 16);
        a2 += __shfl_xor(a2, 16); a3 += __shfl_xor(a3, 16);
        a4 += __shfl_xor(a4, 16); a5 += __shfl_xor(a5, 16);
        a6 += __shfl_xor(a6, 16); a7 += __shfl_xor(a7, 16);
        if (sub == 0) {
            int c = (l31 & 15) * 8;
            float4 bgv0 = *(const float4*)&bg[c];
            float4 bgv1 = *(const float4*)&bg[c + 4];
            float4 z0, z1;
            z0.x = a0 + bgv0.x; z0.y = a1 + bgv0.y;
            z0.z = a2 + bgv0.z; z0.w = a3 + bgv0.w;
            z1.x = a4 + bgv1.x; z1.y = a5 + bgv1.y;
            z1.z = a6 + bgv1.z; z1.w = a7 + bgv1.w;
            z0.x = z0.x > 0.f ? z0.x : __expf(z0.x) - 1.f;
            z0.y = z0.y > 0.f ? z0.y : __expf(z0.y) - 1.f;
            z0.z = z0.z > 0.f ? z0.z : __expf(z0.z) - 1.f;
            z0.w = z0.w > 0.f ? z0.w : __expf(z0.w) - 1.f;
            z1.x = z1.x > 0.f ? z1.x : __expf(z1.x) - 1.f;
            z1.y = z1.y > 0.f ? z1.y : __expf(z1.y) - 1.f;
            z1.z = z1.z > 0.f ? z1.z : __expf(z1.z) - 1.f;
            z1.w = z1.w > 0.f ? z1.w : __expf(z1.w) - 1.f;
            *(float4*)&zout[c] = z0;
            *(float4*)&zout[c + 4] = z1;
        }
    } else {
        // rare: 32-lane strided generic path, with max
        float lmax = -INFINITY;
        for (int i = l31; i < deg; i += 32) {
            int s = perm[o0 + i];
            float x = el[s] + erb;
            x = x >= 0.f ? x : NEG_SLOPE * x;
            lmax = fmaxf(lmax, x);
        }
        #pragma unroll
        for (int msk = 1; msk < 32; msk <<= 1) lmax = fmaxf(lmax, __shfl_xor(lmax, msk));
        float lsum = 0.f;
        for (int i = l31; i < deg; i += 32) {
            int s = perm[o0 + i];
            float x = el[s] + erb;
            x = x >= 0.f ? x : NEG_SLOPE * x;
            lsum += __expf(x - lmax);
        }
        #pragma unroll
        for (int msk = 1; msk < 32; msk <<= 1) lsum += __shfl_xor(lsum, msk);
        float invz = 1.f / lsum;
        float c0 = 0.f, c1 = 0.f, c2 = 0.f, c3 = 0.f;
        for (int j = 0; j < deg; j++) {
            int s = perm[o0 + j];
            float x = el[s] + erb;
            x = x >= 0.f ? x : NEG_SLOPE * x;
            float e_ = __expf(x - lmax) * invz;
            uint2 hv = *(const uint2*)(hsr + (size_t)s * 128 + l31 * 4);
            c0 = fmaf(e_, bflo(hv.x), c0);
            c1 = fmaf(e_, bfhi(hv.x), c1);
            c2 = fmaf(e_, bflo(hv.y), c2);
            c3 = fmaf(e_, bfhi(hv.y), c3);
        }
        int c = l31 * 4;
        float4 bgv = *(const float4*)&bg[c];
        float4 z;
        z.x = c0 + bgv.x; z.y = c1 + bgv.y;
        z.z = c2 + bgv.z; z.w = c3 + bgv.w;
        z.x = z.x > 0.f ? z.x : __expf(z.x) - 1.f;
        z.y = z.y > 0.f ? z.y : __expf(z.y) - 1.f;
        z.z = z.z > 0.f ? z.z : __expf(z.z) - 1.f;
        z.w = z.w > 0.f ? z.w : __expf(z.w) - 1.f;
        *(float4*)&zout[c] = z;
    }
}

// ---------------------------------------------------------------------------
// semantic attention via bf16 MFMA — persistent grid-stride (Wt staged once).
__global__ __launch_bounds__(256) void semantic_kernel(
        const float* __restrict__ zm, const ushort_t* __restrict__ Wt_g,
        const float* __restrict__ b1, const float* __restrict__ W2,
        float* __restrict__ w_sum) {
    __shared__ ushort_t Wt[128 * 136];
    __shared__ float hsum[3];
    const int NROWS = N_DST * 3;
    int tid = threadIdx.x;
    if (tid < 3) hsum[tid] = 0.f;

    #pragma unroll
    for (int i = 0; i < 8; i++) {
        int c = i * 256 + tid;
        int n = c >> 4, c16 = c & 15;
        uint4 t = *(const uint4*)(Wt_g + n * 128 + c16 * 8);
        *(uint4*)&Wt[n * 136 + c16 * 8] = t;
    }
    __syncthreads();

    int w    = tid >> 6, lane = tid & 63;
    int quad = lane >> 4, l15 = lane & 15;

    for (int tile = blockIdx.x; tile < SEM_TILES; tile += gridDim.x) {
        long row0 = (long)tile * 64 + w * 16;
        long rA = row0 + l15; if (rA > NROWS - 1) rA = NROWS - 1;

        f32x4 acc[8] = {};
        #pragma unroll
        for (int kc = 0; kc < 4; kc++) {
            int k0 = kc * 32 + quad * 8;
            const float* src = zm + (size_t)rA * 128 + k0;
            float4 f0 = *(const float4*)src;
            float4 f1 = *(const float4*)(src + 4);
            bf16x8 a;
            a[0] = (short)f2bf(f0.x); a[1] = (short)f2bf(f0.y);
            a[2] = (short)f2bf(f0.z); a[3] = (short)f2bf(f0.w);
            a[4] = (short)f2bf(f1.x); a[5] = (short)f2bf(f1.y);
            a[6] = (short)f2bf(f1.z); a[7] = (short)f2bf(f1.w);
            #pragma unroll
            for (int nt = 0; nt < 8; nt++) {
                int n = nt * 16 + l15;
                bf16x8 bfr = *(const bf16x8*)&Wt[n * 136 + k0];
                acc[nt] = __builtin_amdgcn_mfma_f32_16x16x32_bf16(a, bfr, acc[nt], 0, 0, 0);
            }
        }

        float part[4] = {0.f, 0.f, 0.f, 0.f};
        #pragma unroll
        for (int nt = 0; nt < 8; nt++) {
            int n = nt * 16 + l15;
            float bbn = b1[n], ww = W2[n];
            #pragma unroll
            for (int i = 0; i < 4; i++) {
                float t = tanh_fast(acc[nt][i] + bbn);
                part[i] = fmaf(t, ww, part[i]);
            }
        }
        #pragma unroll
        for (int msk = 1; msk < 16; msk <<= 1)
            #pragma unroll
            for (int i = 0; i < 4; i++) part[i] += __shfl_xor(part[i], msk);
        if (l15 == 0) {
            #pragma unroll
            for (int i = 0; i < 4; i++) {
                long R = row0 + quad * 4 + i;
                if (R < NROWS) atomicAdd(&hsum[(int)(R % 3)], part[i]);
            }
        }
    }
    __syncthreads();
    if (tid < 3) atomicAdd(&w_sum[tid], hsum[tid]);
}

// ---------------------------------------------------------------------------
__global__ void combine_kernel(const float* __restrict__ zm, const float* __restrict__ w_sum,
                               float* __restrict__ out, float* __restrict__ out_att) {
    float w0 = w_sum[0] * (1.f / (float)N_DST);
    float w1 = w_sum[1] * (1.f / (float)N_DST);
    float w2 = w_sum[2] * (1.f / (float)N_DST);
    float m = fmaxf(w0, fmaxf(w1, w2));
    float e0 = __expf(w0 - m), e1 = __expf(w1 - m), e2 = __expf(w2 - m);
    float s = 1.f / (e0 + e1 + e2);
    float a0 = e0 * s, a1 = e1 * s, a2 = e2 * s;
    if (blockIdx.x == 0 && threadIdx.x < 3)
        out_att[threadIdx.x] = threadIdx.x == 0 ? a0 : (threadIdx.x == 1 ? a1 : a2);
    int id4 = blockIdx.x * 256 + threadIdx.x;
    int n  = id4 >> 5;
    int d4 = (id4 & 31) * 4;
    const float4 z0 = *(const float4*)&zm[((size_t)n * 3 + 0) * 128 + d4];
    const float4 z1 = *(const float4*)&zm[((size_t)n * 3 + 1) * 128 + d4];
    const float4 z2 = *(const float4*)&zm[((size_t)n * 3 + 2) * 128 + d4];
    float4 o;
    o.x = a0 * z0.x + a1 * z1.x + a2 * z2.x;
    o.y = a0 * z0.y + a1 * z1.y + a2 * z2.y;
    o.z = a0 * z0.z + a1 * z1.z + a2 * z2.z;
    o.w = a0 * z0.w + a1 * z1.w + a2 * z2.w;
    *(float4*)&out[(size_t)n * 128 + d4] = o;
}

// ---------------------------------------------------------------------------
extern "C" void kernel_launch(void* const* d_in, const int* in_sizes, int n_in,
                              void* d_out, int out_size, void* d_ws, size_t ws_size,
                              hipStream_t stream) {
    const float* dstf   = (const float*)d_in[0];
    const float* src0   = (const float*)d_in[1];
    const float* src1   = (const float*)d_in[2];
    const float* src2   = (const float*)d_in[3];
    const float* sem_W1 = (const float*)d_in[4];
    const float* sem_b1 = (const float*)d_in[5];
    const float* sem_W2 = (const float*)d_in[6];
    const float* Wg[3]  = {(const float*)d_in[7],  (const float*)d_in[13], (const float*)d_in[19]};
    const float* al[3]  = {(const float*)d_in[8],  (const float*)d_in[14], (const float*)d_in[20]};
    const float* ar[3]  = {(const float*)d_in[9],  (const float*)d_in[15], (const float*)d_in[21]};
    const float* bg[3]  = {(const float*)d_in[10], (const float*)d_in[16], (const float*)d_in[22]};
    const int*  sidx[3] = {(const int*)d_in[11], (const int*)d_in[17], (const int*)d_in[23]};
    const int*  didx[3] = {(const int*)d_in[12], (const int*)d_in[18], (const int*)d_in[24]};
    float* out = (float*)d_out;

    char* p = (char*)d_ws;
    auto alloc = [&](size_t bytes) -> char* {
        char* q = p; p += (bytes + 255) & ~(size_t)255; return q;
    };
    float*    zm   = (float*)alloc((size_t)N_DST * 3 * 128 * 4);    // 76.8 MB (pairs aliases)
    ushort_t* hs   = (ushort_t*)alloc((size_t)3 * N_SRC * 128 * 2); // 38.4 MB bf16
    float*    elv  = (float*)alloc((size_t)6 * N_DST * 4);
    float*    wv   = (float*)alloc((size_t)3 * 128 * 4);
    ushort_t* Wt_g = (ushort_t*)alloc((size_t)128 * 128 * 2);
    ushort_t* Bv   = (ushort_t*)alloc((size_t)3 * 32768 * 2);       // fragment-linear B
    int* cnts = (int*)alloc((size_t)3 * N_DST * 4);
    int* offs = (int*)alloc((size_t)3 * N_DST * 4);
    int* perm = (int*)alloc((size_t)3 * NB * CAP * 4);              // 10.8 MB
    int* zero = (int*)alloc((size_t)(3 * NB + 8) * 4);              // bucketCur + wsum
    int*   bucketCur = zero;
    float* wsum      = (float*)(zero + 3 * NB);
    int2* pairs = (int2*)zm;    // 21.7 MB alias; dead before aggregate writes zm

    hipMemsetAsync(zero, 0, (size_t)(3 * NB + 8) * 4, stream);

    prep_scatter_kernel<<<259 + 3 * NBLK_REL, 256, 0, stream>>>(
        Wg[0], Wg[1], Wg[2], ar[0], ar[1], ar[2], sem_W1, wv, Wt_g, Bv,
        didx[0], didx[1], didx[2], sidx[0], sidx[1], sidx[2], bucketCur, pairs);
    csr_gemm_kernel<<<GEMM_GRID + CSR_GRID, 512, 0, stream>>>(
        src0, src1, src2, Bv, al[0], al[1], al[2], dstf, wv, hs, elv,
        pairs, bucketCur, offs, cnts, perm);
    aggregate_kernel<<<3 * 6250, 256, 0, stream>>>(hs, elv, perm, offs, cnts,
                                                   bg[0], bg[1], bg[2], zm);
    semantic_kernel<<<SEM_GRID, 256, 0, stream>>>(zm, Wt_g, sem_b1, sem_W2, wsum);
    combine_kernel<<<6250, 256, 0, stream>>>(zm, wsum, out, out + (size_t)N_DST * 128);
}